// Round 5
// baseline (271.746 us; speedup 1.0000x reference)
//
#include <hip/hip_runtime.h>

#define B_ 256
#define S_ 512
#define V_ 50000
#define D_ 256
#define L_ 128
#define LGRID 1024

typedef __attribute__((ext_vector_type(8))) short short8;
typedef __attribute__((ext_vector_type(4))) float floatx4;

// ws layout (float/int units):
// [0] unused, [1] kl_acc (f32), [2] unused, [3] wl_cnt (i32)
// [16 .. +256)      lens (i32)
// [272 .. +65536)   Q (256x256 f32)
// [65808 .. +2304)  worklist ints: (b<<8)|tile
// [68112 .. +32768) Wt (256x256 bf16 = 65536 shorts = 32768 floats)
// [100880 .. +256)  sq partial slots (f32)
// [101136 .. +64)   valid-count partial slots (i32)
#define OFF_LENS 16
#define OFF_Q    (OFF_LENS + B_)
#define OFF_WL   (OFF_Q + B_ * D_)
#define OFF_WT   (OFF_WL + 2304)
#define OFF_SQP  (OFF_WT + 32768)   // FIXED: Wt is 32768 floats, not 16384
#define OFF_VCP  (OFF_SQP + 256)

__device__ __forceinline__ unsigned short f2bf(float x) {
    unsigned u = __float_as_uint(x);
    u += 0x7FFFu + ((u >> 16) & 1u);
    return (unsigned short)(u >> 16);
}
__device__ __forceinline__ unsigned pk2(float a, float b) {
    return (unsigned)f2bf(a) | ((unsigned)f2bf(b) << 16);
}

// ---- Wout (f32 [k][n]) -> Wt (bf16 [n][k]); also zero all accumulator slots ----
__global__ __launch_bounds__(256) void wt_kernel(const float* __restrict__ Wout,
                                                 unsigned short* __restrict__ Wt,
                                                 float* __restrict__ ws) {
    __shared__ float sT[64][65];
    if (blockIdx.x == 0 && blockIdx.y == 0) {
        int t = threadIdx.x;
        if (t < 4) ((int*)ws)[t] = 0;
        ws[OFF_SQP + t] = 0.f;
        if (t < 64) ((int*)ws)[OFF_VCP + t] = 0;
    }
    const int k0 = blockIdx.x * 64, n0 = blockIdx.y * 64;
    const int c = threadIdx.x & 63, rg = threadIdx.x >> 6;
#pragma unroll
    for (int i = 0; i < 16; ++i) {
        int r = rg * 16 + i;
        sT[c][r] = Wout[(k0 + r) * D_ + n0 + c];
    }
    __syncthreads();
#pragma unroll
    for (int i = 0; i < 16; ++i) {
        int r = rg * 16 + i;
        Wt[(size_t)(n0 + r) * D_ + k0 + c] = f2bf(sT[r][c]);
    }
}

// ---- fused enc + latent + worklist plan (one block per b) ----
__global__ __launch_bounds__(1024) void enclat_kernel(
    const int* __restrict__ vocab, const int* __restrict__ order,
    const int* __restrict__ mask, const float* __restrict__ emb,
    const float* __restrict__ eps,
    const float* __restrict__ Wm, const float* __restrict__ bm,
    const float* __restrict__ Wv, const float* __restrict__ bv,
    const float* __restrict__ Wlin, const float* __restrict__ blin,
    const float* __restrict__ Wout, const float* __restrict__ bout,
    int* __restrict__ lens, float* __restrict__ Q,
    int* __restrict__ wl, int* __restrict__ ctrl) {
    __shared__ int s_id1[S_], s_id2[S_];
    __shared__ float4 s_part[15 * 64];
    __shared__ float s_enc[D_];
    __shared__ float s_mean[L_], s_lv[L_], s_z[L_], s_mem[D_];
    __shared__ float s_red[256];
    __shared__ int s_cnt;
    const int b = blockIdx.x;
    const int tid = threadIdx.x;
    if (tid == 0) s_cnt = 0;
    __syncthreads();
    if (tid < S_) {
        int j = tid;
        int mk = mask[b * S_ + j];
        int id1 = 0, id2 = 0;
        if (mk) {
            id1 = vocab[b * S_ + j];
            if (j == 0) {
                id2 = 1;  // BOS at position 0
            } else {
                int oi = order[(size_t)(b * S_ + j) * 6];
                if (oi == -1) oi = 1;
                id2 = mask[b * S_ + oi] ? vocab[b * S_ + oi] : 0;  // parent from vt
            }
        }
        s_id1[j] = id1;
        s_id2[j] = id2;
        unsigned long long bal = __ballot(mk != 0);
        if ((tid & 63) == 0) atomicAdd(&s_cnt, __popcll(bal));
    }
    __syncthreads();
    const int cnt = s_cnt;  // prefix mask: valid j = [0, cnt)
    if (tid == 0) {
        lens[b] = cnt;
        int nt = (cnt >> 6) + 1;  // tiles cover j in [0, cnt]
        int base = atomicAdd(&ctrl[3], nt);
        for (int t = 0; t < nt; ++t) wl[base + t] = (b << 8) | t;
    }
    const int jg = tid >> 6, d4 = tid & 63;
    const float4* emb4 = (const float4*)emb;
    float4 a = {0.f, 0.f, 0.f, 0.f};
#pragma unroll 4
    for (int j = jg; j < cnt; j += 16) {
        float4 x = emb4[(size_t)s_id1[j] * 64 + d4];
        float4 y = emb4[(size_t)s_id2[j] * 64 + d4];
        a.x += x.x + y.x; a.y += x.y + y.y; a.z += x.z + y.z; a.w += x.w + y.w;
    }
    if (jg) s_part[(jg - 1) * 64 + d4] = a;
    __syncthreads();
    if (jg == 0) {
#pragma unroll
        for (int g = 0; g < 15; ++g) {
            float4 p = s_part[g * 64 + d4];
            a.x += p.x; a.y += p.y; a.z += p.z; a.w += p.w;
        }
        float inv = 1.f / fmaxf((float)cnt, 1.f);
        a.x *= inv; a.y *= inv; a.z *= inv; a.w *= inv;
        ((float4*)s_enc)[d4] = a;
    }
    __syncthreads();
    float dot = 0.f;
    if (tid < 256) {
        const int l = tid & (L_ - 1);
        const float* W = (tid < L_) ? Wm : Wv;
        const float* bb = (tid < L_) ? bm : bv;
        dot = bb[l];
        for (int d = 0; d < D_; ++d) dot = fmaf(s_enc[d], W[d * L_ + l], dot);
        if (tid < L_) s_mean[l] = dot; else s_lv[l] = dot;
    }
    __syncthreads();
    float klp = 0.f;
    if (tid < L_) {
        float mn = s_mean[tid], lv = s_lv[tid];
        s_z[tid] = mn + eps[b * L_ + tid] * expf(0.5f * lv);
        klp = 1.f + lv - mn * mn - expf(lv);
    }
    if (tid < 256) s_red[tid] = klp;
    __syncthreads();
    for (int s = 128; s > 0; s >>= 1) {
        if (tid < s) s_red[tid] += s_red[tid + s];
        __syncthreads();
    }
    if (tid == 0) atomicAdd((float*)&ctrl[1], s_red[0]);
    if (tid < 256) {
        float mem = blin[tid];
        for (int l2 = 0; l2 < L_; ++l2) mem = fmaf(s_z[l2], Wlin[l2 * D_ + tid], mem);
        s_mem[tid] = mem;
    }
    __syncthreads();
    if (tid < 256) {
        float qv = bout[tid];
        for (int k = 0; k < D_; ++k) qv = fmaf(s_mem[k], Wout[k * D_ + tid], qv);
        Q[b * D_ + tid] = qv;
    }
}

// ---- loss: barrier-free, LDS-free, direct-to-register bf16 MFMA ----
__global__ __launch_bounds__(256, 3) void loss_kernel(
    const int* __restrict__ vocab, const float* __restrict__ emb,
    const unsigned short* __restrict__ Wt, const float* __restrict__ Q,
    const int* __restrict__ lens, const int* __restrict__ wl,
    const int* __restrict__ ctrl, float* __restrict__ sqp,
    int* __restrict__ vcp) {
    const int tid = threadIdx.x;
    const int wv = tid >> 6, lane = tid & 63;
    const int lo = lane & 15, hi = lane >> 4;
    const int nwork = ctrl[3];

    for (int it = blockIdx.x; it < nwork; it += LGRID) {
        const int e = wl[it];
        const int b = e >> 8;
        const int mt0 = (e & 255) << 6;
        const int len = lens[b];

        // lane-computed A-row ids (rows m = mt*16 + lo)
        int aid[4];
#pragma unroll
        for (int mt = 0; mt < 4; ++mt) {
            int j = mt0 + mt * 16 + lo;
            aid[mt] = (j <= len) ? ((j == 0) ? 1 : vocab[b * S_ + j - 1]) : 0;
        }
        // lane-computed tgt ids (rows = mt*16 + hi*4 + r)
        int tgid[16];
#pragma unroll
        for (int mt = 0; mt < 4; ++mt)
#pragma unroll
            for (int r = 0; r < 4; ++r) {
                int j = mt0 + mt * 16 + hi * 4 + r;
                int tg = -1;
                if (j <= len) tg = (j < len) ? vocab[b * S_ + j] : ((len < S_) ? 2 : 1);
                tgid[mt * 4 + r] = tg;
            }

        floatx4 acc[4][4];
#pragma unroll
        for (int mt = 0; mt < 4; ++mt)
#pragma unroll
            for (int nt = 0; nt < 4; ++nt) acc[mt][nt] = (floatx4){0.f, 0.f, 0.f, 0.f};

        const unsigned short* wrow = Wt + (size_t)(wv * 64 + lo) * D_ + hi * 8;
        const float* arow0 = emb + (size_t)aid[0] * D_ + hi * 8;
        const float* arow1 = emb + (size_t)aid[1] * D_ + hi * 8;
        const float* arow2 = emb + (size_t)aid[2] * D_ + hi * 8;
        const float* arow3 = emb + (size_t)aid[3] * D_ + hi * 8;

        for (int kk = 0; kk < 8; ++kk) {
            const int k0 = kk * 32;
            short8 bfr[4];
#pragma unroll
            for (int nt = 0; nt < 4; ++nt)
                bfr[nt] = *(const short8*)(wrow + nt * 16 * D_ + k0);
            const float* ar[4] = {arow0 + k0, arow1 + k0, arow2 + k0, arow3 + k0};
#pragma unroll
            for (int mt = 0; mt < 4; ++mt) {
                float4 f0 = *(const float4*)(ar[mt]);
                float4 f1 = *(const float4*)(ar[mt] + 4);
                union { unsigned u[4]; short8 s; } cv;
                cv.u[0] = pk2(f0.x, f0.y);
                cv.u[1] = pk2(f0.z, f0.w);
                cv.u[2] = pk2(f1.x, f1.y);
                cv.u[3] = pk2(f1.z, f1.w);
#pragma unroll
                for (int nt = 0; nt < 4; ++nt)
                    acc[mt][nt] = __builtin_amdgcn_mfma_f32_16x16x32_bf16(
                        cv.s, bfr[nt], acc[mt][nt], 0, 0, 0);
            }
        }

        // epilogue: D[row][col] at col=lo, row=hi*4+r
        float lsum = 0.f;
#pragma unroll
        for (int nt = 0; nt < 4; ++nt) {
            const int n = wv * 64 + nt * 16 + lo;
            const float qv = Q[b * D_ + n];
#pragma unroll
            for (int mt = 0; mt < 4; ++mt) {
#pragma unroll
                for (int r = 0; r < 4; ++r) {
                    const int tg = tgid[mt * 4 + r];
                    if (tg >= 0) {
                        float t = emb[(size_t)tg * D_ + n];
                        float d = acc[mt][nt][r] + qv - t;
                        lsum = fmaf(d, d, lsum);
                    }
                }
            }
        }
#pragma unroll
        for (int off = 32; off; off >>= 1) lsum += __shfl_down(lsum, off, 64);
        if (lane == 0) atomicAdd(&sqp[blockIdx.x & 255], lsum);
        if (tid == 0) atomicAdd(&vcp[blockIdx.x & 63], min(len, mt0 + 63) - mt0 + 1);
    }
}

__global__ __launch_bounds__(256) void finalize_kernel(const float* __restrict__ ws,
                                                       float* __restrict__ out) {
    __shared__ float s_sq[256];
    const int tid = threadIdx.x;
    s_sq[tid] = ws[OFF_SQP + tid];
    __syncthreads();
    for (int s = 128; s > 0; s >>= 1) {
        if (tid < s) s_sq[tid] += s_sq[tid + s];
        __syncthreads();
    }
    if (tid == 0) {
        int vc = 0;
        for (int i = 0; i < 64; ++i) vc += ((const int*)ws)[OFF_VCP + i];
        long long denom = (long long)vc * D_;
        if (denom < 1) denom = 1;
        out[0] = s_sq[0] / (float)denom;
        out[1] = -0.5f * ws[1] / (float)B_;
    }
}

extern "C" void kernel_launch(void* const* d_in, const int* in_sizes, int n_in,
                              void* d_out, int out_size, void* d_ws, size_t ws_size,
                              hipStream_t stream) {
    const int* vocab = (const int*)d_in[0];
    const int* order = (const int*)d_in[1];
    const int* mask  = (const int*)d_in[2];
    const float* eps  = (const float*)d_in[3];
    const float* emb  = (const float*)d_in[4];
    const float* Wm   = (const float*)d_in[5];
    const float* bm   = (const float*)d_in[6];
    const float* Wv   = (const float*)d_in[7];
    const float* bv   = (const float*)d_in[8];
    const float* Wlin = (const float*)d_in[9];
    const float* blin = (const float*)d_in[10];
    const float* Wout = (const float*)d_in[11];
    const float* bout = (const float*)d_in[12];

    float* ws = (float*)d_ws;
    int* ctrl = (int*)ws;
    int* lens = (int*)(ws + OFF_LENS);
    float* Q = ws + OFF_Q;
    int* wl = (int*)(ws + OFF_WL);
    unsigned short* Wt = (unsigned short*)(ws + OFF_WT);
    float* sqp = ws + OFF_SQP;
    int* vcp = (int*)(ws + OFF_VCP);

    wt_kernel<<<dim3(4, 4), 256, 0, stream>>>(Wout, Wt, ws);
    enclat_kernel<<<B_, 1024, 0, stream>>>(vocab, order, mask, emb, eps, Wm, bm,
                                           Wv, bv, Wlin, blin, Wout, bout,
                                           lens, Q, wl, ctrl);
    loss_kernel<<<LGRID, 256, 0, stream>>>(vocab, emb, Wt, Q, lens, wl, ctrl,
                                           sqp, vcp);
    finalize_kernel<<<1, 256, 0, stream>>>(ws, (float*)d_out);
}

// Round 6
// 227.445 us; speedup vs baseline: 1.1948x; 1.1948x over previous
//
#include <hip/hip_runtime.h>

#define B_ 256
#define S_ 512
#define V_ 50000
#define D_ 256
#define L_ 128

typedef __attribute__((ext_vector_type(8))) short short8;
typedef __attribute__((ext_vector_type(4))) float floatx4;

// ws layout (float/int units):
// [0] unused, [1] kl_acc (f32), [2..16) unused
// [16 .. +256)      lens (i32)
// [272 .. +65536)   Q (256x256 f32)
// [65808 .. +32768) Wt (256x256 bf16 = Wout^T)
// [98576 .. +256)   sq partial slots (f32)
// [98832 .. +6400000) P (50000x256 bf16 = emb @ Wout)
#define OFF_LENS 16
#define OFF_Q    (OFF_LENS + B_)
#define OFF_WL_UNUSED 0
#define OFF_WT   (OFF_Q + B_ * D_)
#define OFF_SQP  (OFF_WT + 32768)
#define OFF_P    (OFF_SQP + 256)

__device__ __forceinline__ unsigned short f2bf(float x) {
    unsigned u = __float_as_uint(x);
    u += 0x7FFFu + ((u >> 16) & 1u);
    return (unsigned short)(u >> 16);
}
__device__ __forceinline__ unsigned pk2(float a, float b) {
    return (unsigned)f2bf(a) | ((unsigned)f2bf(b) << 16);
}
__device__ __forceinline__ float bf2f(unsigned short u) {
    return __uint_as_float(((unsigned)u) << 16);
}

// ---- Wout (f32 [k][n]) -> Wt (bf16 [n][k]); zero accumulator slots ----
__global__ __launch_bounds__(256) void wt_kernel(const float* __restrict__ Wout,
                                                 unsigned short* __restrict__ Wt,
                                                 float* __restrict__ ws) {
    __shared__ float sT[64][65];
    if (blockIdx.x == 0 && blockIdx.y == 0) {
        int t = threadIdx.x;
        if (t < 16) ((int*)ws)[t] = 0;   // incl. kl_acc at [1]
        ws[OFF_SQP + t] = 0.f;
    }
    const int k0 = blockIdx.x * 64, n0 = blockIdx.y * 64;
    const int c = threadIdx.x & 63, rg = threadIdx.x >> 6;
#pragma unroll
    for (int i = 0; i < 16; ++i) {
        int r = rg * 16 + i;
        sT[c][r] = Wout[(k0 + r) * D_ + n0 + c];
    }
    __syncthreads();
#pragma unroll
    for (int i = 0; i < 16; ++i) {
        int r = rg * 16 + i;
        Wt[(size_t)(n0 + r) * D_ + k0 + c] = f2bf(sT[r][c]);
    }
}

// ---- fused enc + latent (one block per b) ----
__global__ __launch_bounds__(1024) void enclat_kernel(
    const int* __restrict__ vocab, const int* __restrict__ order,
    const int* __restrict__ mask, const float* __restrict__ emb,
    const float* __restrict__ eps,
    const float* __restrict__ Wm, const float* __restrict__ bm,
    const float* __restrict__ Wv, const float* __restrict__ bv,
    const float* __restrict__ Wlin, const float* __restrict__ blin,
    const float* __restrict__ Wout, const float* __restrict__ bout,
    int* __restrict__ lens, float* __restrict__ Q, float* __restrict__ kl_acc) {
    __shared__ int s_id1[S_], s_id2[S_];
    __shared__ float4 s_part[15 * 64];
    __shared__ float s_enc[D_];
    __shared__ float s_mean[L_], s_lv[L_], s_z[L_], s_mem[D_];
    __shared__ float s_red[256];
    __shared__ int s_cnt;
    const int b = blockIdx.x;
    const int tid = threadIdx.x;
    if (tid == 0) s_cnt = 0;
    __syncthreads();
    if (tid < S_) {
        int j = tid;
        int mk = mask[b * S_ + j];
        int id1 = 0, id2 = 0;
        if (mk) {
            id1 = vocab[b * S_ + j];
            if (j == 0) {
                id2 = 1;  // BOS at position 0
            } else {
                int oi = order[(size_t)(b * S_ + j) * 6];
                if (oi == -1) oi = 1;
                id2 = mask[b * S_ + oi] ? vocab[b * S_ + oi] : 0;  // parent from vt
            }
        }
        s_id1[j] = id1;
        s_id2[j] = id2;
        unsigned long long bal = __ballot(mk != 0);
        if ((tid & 63) == 0) atomicAdd(&s_cnt, __popcll(bal));
    }
    __syncthreads();
    const int cnt = s_cnt;  // prefix mask: valid j = [0, cnt)
    if (tid == 0) lens[b] = cnt;
    const int jg = tid >> 6, d4 = tid & 63;
    const float4* emb4 = (const float4*)emb;
    float4 a = {0.f, 0.f, 0.f, 0.f};
#pragma unroll 4
    for (int j = jg; j < cnt; j += 16) {
        float4 x = emb4[(size_t)s_id1[j] * 64 + d4];
        float4 y = emb4[(size_t)s_id2[j] * 64 + d4];
        a.x += x.x + y.x; a.y += x.y + y.y; a.z += x.z + y.z; a.w += x.w + y.w;
    }
    if (jg) s_part[(jg - 1) * 64 + d4] = a;
    __syncthreads();
    if (jg == 0) {
#pragma unroll
        for (int g = 0; g < 15; ++g) {
            float4 p = s_part[g * 64 + d4];
            a.x += p.x; a.y += p.y; a.z += p.z; a.w += p.w;
        }
        float inv = 1.f / fmaxf((float)cnt, 1.f);
        a.x *= inv; a.y *= inv; a.z *= inv; a.w *= inv;
        ((float4*)s_enc)[d4] = a;
    }
    __syncthreads();
    float dot = 0.f;
    if (tid < 256) {
        const int l = tid & (L_ - 1);
        const float* W = (tid < L_) ? Wm : Wv;
        const float* bb = (tid < L_) ? bm : bv;
        dot = bb[l];
        for (int d = 0; d < D_; ++d) dot = fmaf(s_enc[d], W[d * L_ + l], dot);
        if (tid < L_) s_mean[l] = dot; else s_lv[l] = dot;
    }
    __syncthreads();
    float klp = 0.f;
    if (tid < L_) {
        float mn = s_mean[tid], lv = s_lv[tid];
        s_z[tid] = mn + eps[b * L_ + tid] * expf(0.5f * lv);
        klp = 1.f + lv - mn * mn - expf(lv);
    }
    if (tid < 256) s_red[tid] = klp;
    __syncthreads();
    for (int s = 128; s > 0; s >>= 1) {
        if (tid < s) s_red[tid] += s_red[tid + s];
        __syncthreads();
    }
    if (tid == 0) atomicAdd(kl_acc, s_red[0]);
    if (tid < 256) {
        float mem = blin[tid];
        for (int l2 = 0; l2 < L_; ++l2) mem = fmaf(s_z[l2], Wlin[l2 * D_ + tid], mem);
        s_mem[tid] = mem;
    }
    __syncthreads();
    if (tid < 256) {
        float qv = bout[tid];
        for (int k = 0; k < D_; ++k) qv = fmaf(s_mem[k], Wout[k * D_ + tid], qv);
        Q[b * D_ + tid] = qv;
    }
}

// ---- P = emb @ Wout, bf16 out. Contiguous rows: register-direct A, no LDS ----
// wave wv handles rows [blk*64 + wv*16, +16) x all 256 cols
__global__ __launch_bounds__(256) void pgemm_kernel(
    const float* __restrict__ emb, const unsigned short* __restrict__ Wt,
    unsigned short* __restrict__ P) {
    const int tid = threadIdx.x;
    const int wv = tid >> 6, lane = tid & 63;
    const int lo = lane & 15, hi = lane >> 4;
    const int rowA = min(blockIdx.x * 64 + wv * 16 + lo, V_ - 1);
    const float* arow = emb + (size_t)rowA * D_ + hi * 8;
    const unsigned short* wrow = Wt + (size_t)lo * D_ + hi * 8;

    floatx4 acc[16];
#pragma unroll
    for (int nt = 0; nt < 16; ++nt) acc[nt] = (floatx4){0.f, 0.f, 0.f, 0.f};

#pragma unroll
    for (int kk = 0; kk < 8; ++kk) {
        const int k0 = kk * 32;
        float4 f0 = *(const float4*)(arow + k0);
        float4 f1 = *(const float4*)(arow + k0 + 4);
        union { unsigned u[4]; short8 s; } cv;
        cv.u[0] = pk2(f0.x, f0.y);
        cv.u[1] = pk2(f0.z, f0.w);
        cv.u[2] = pk2(f1.x, f1.y);
        cv.u[3] = pk2(f1.z, f1.w);
#pragma unroll
        for (int nt = 0; nt < 16; ++nt) {
            short8 bfr = *(const short8*)(wrow + (size_t)(nt * 16) * D_ + k0);
            acc[nt] = __builtin_amdgcn_mfma_f32_16x16x32_bf16(cv.s, bfr, acc[nt], 0, 0, 0);
        }
    }
    // store: row = blk*64 + wv*16 + hi*4 + r, col = nt*16 + lo
    const int rowbase = blockIdx.x * 64 + wv * 16 + hi * 4;
#pragma unroll
    for (int r = 0; r < 4; ++r) {
        const int row = rowbase + r;
        if (row < V_) {
            unsigned short* prow = P + (size_t)row * D_ + lo;
#pragma unroll
            for (int nt = 0; nt < 16; ++nt) prow[nt * 16] = f2bf(acc[nt][r]);
        }
    }
}

// ---- scan: per position d = P[inp] + Q_b - emb[tgt]; sum d^2 ----
// one wave per position; lane covers 4 cols. 17 chunks x 32 positions per b.
__global__ __launch_bounds__(256) void scan_kernel(
    const int* __restrict__ vocab, const float* __restrict__ emb,
    const unsigned short* __restrict__ P, const float* __restrict__ Q,
    const int* __restrict__ lens, float* __restrict__ sqp) {
    const int tid = threadIdx.x;
    const int wv = tid >> 6, lane = tid & 63;
    const int blk = blockIdx.x;
    const int b = blk / 17, chunk = blk % 17;
    const int len = lens[b];
    const int j0 = chunk * 32 + wv * 8;
    if (j0 > len) return;  // wave-uniform

    const int c = lane * 4;
    const float4 q4 = *(const float4*)(Q + (size_t)b * D_ + c);
    float acc = 0.f;
#pragma unroll 2
    for (int jj = 0; jj < 8; ++jj) {
        const int j = j0 + jj;
        if (j > len) break;  // wave-uniform
        const int inp = (j == 0) ? 1 : vocab[b * S_ + j - 1];
        const int tgt = (j < len) ? vocab[b * S_ + j] : ((len < S_) ? 2 : 1);
        const ushort4 pv = *(const ushort4*)(P + (size_t)inp * D_ + c);
        const float4 tv = *(const float4*)(emb + (size_t)tgt * D_ + c);
        float d0 = bf2f(pv.x) + q4.x - tv.x;
        float d1 = bf2f(pv.y) + q4.y - tv.y;
        float d2 = bf2f(pv.z) + q4.z - tv.z;
        float d3 = bf2f(pv.w) + q4.w - tv.w;
        acc = fmaf(d0, d0, acc);
        acc = fmaf(d1, d1, acc);
        acc = fmaf(d2, d2, acc);
        acc = fmaf(d3, d3, acc);
    }
#pragma unroll
    for (int off = 32; off; off >>= 1) acc += __shfl_down(acc, off, 64);
    if (lane == 0) atomicAdd(&sqp[(blk * 4 + wv) & 255], acc);
}

__global__ __launch_bounds__(256) void finalize_kernel(const float* __restrict__ ws,
                                                       float* __restrict__ out) {
    __shared__ float s_sq[256];
    __shared__ int s_vc[256];
    const int tid = threadIdx.x;
    s_sq[tid] = ws[OFF_SQP + tid];
    s_vc[tid] = ((const int*)ws)[OFF_LENS + tid] + 1;  // valid = len + 1 per b
    __syncthreads();
    for (int s = 128; s > 0; s >>= 1) {
        if (tid < s) {
            s_sq[tid] += s_sq[tid + s];
            s_vc[tid] += s_vc[tid + s];
        }
        __syncthreads();
    }
    if (tid == 0) {
        long long denom = (long long)s_vc[0] * D_;
        if (denom < 1) denom = 1;
        out[0] = s_sq[0] / (float)denom;
        out[1] = -0.5f * ws[1] / (float)B_;
    }
}

extern "C" void kernel_launch(void* const* d_in, const int* in_sizes, int n_in,
                              void* d_out, int out_size, void* d_ws, size_t ws_size,
                              hipStream_t stream) {
    const int* vocab = (const int*)d_in[0];
    const int* order = (const int*)d_in[1];
    const int* mask  = (const int*)d_in[2];
    const float* eps  = (const float*)d_in[3];
    const float* emb  = (const float*)d_in[4];
    const float* Wm   = (const float*)d_in[5];
    const float* bm   = (const float*)d_in[6];
    const float* Wv   = (const float*)d_in[7];
    const float* bv   = (const float*)d_in[8];
    const float* Wlin = (const float*)d_in[9];
    const float* blin = (const float*)d_in[10];
    const float* Wout = (const float*)d_in[11];
    const float* bout = (const float*)d_in[12];

    float* ws = (float*)d_ws;
    int* lens = (int*)(ws + OFF_LENS);
    float* Q = ws + OFF_Q;
    unsigned short* Wt = (unsigned short*)(ws + OFF_WT);
    float* sqp = ws + OFF_SQP;
    unsigned short* P = (unsigned short*)(ws + OFF_P);

    wt_kernel<<<dim3(4, 4), 256, 0, stream>>>(Wout, Wt, ws);
    enclat_kernel<<<B_, 1024, 0, stream>>>(vocab, order, mask, emb, eps, Wm, bm,
                                           Wv, bv, Wlin, blin, Wout, bout,
                                           lens, Q, ws + 1);
    pgemm_kernel<<<(V_ + 63) / 64, 256, 0, stream>>>(emb, Wt, P);
    scan_kernel<<<B_ * 17, 256, 0, stream>>>(vocab, emb, P, Q, lens, sqp);
    finalize_kernel<<<1, 256, 0, stream>>>(ws, (float*)d_out);
}

// Round 7
// 201.685 us; speedup vs baseline: 1.3474x; 1.1277x over previous
//
#include <hip/hip_runtime.h>

#define B_ 256
#define S_ 512
#define V_ 50000
#define D_ 256
#define L_ 128
#define PGRID 512

typedef __attribute__((ext_vector_type(8))) short short8;
typedef __attribute__((ext_vector_type(4))) float floatx4;

// ws layout (float units):
// [0] unused, [1] kl_acc (f32), [2..16) unused
// [16 .. +256)        lens (i32)
// [272 .. +65536)     Q (256x256 f32)
// [65808 .. +32768)   Wt (256x256 bf16 = Wout^T)
// [98576 .. +256)     sq partial slots (f32)
// [98832 .. +6400000) embb (50000x256 bf16)
// [6498832 .. +6400000) P (50000x256 bf16 = emb @ Wout)
#define OFF_LENS 16
#define OFF_Q    (OFF_LENS + B_)
#define OFF_WT   (OFF_Q + B_ * D_)
#define OFF_SQP  (OFF_WT + 32768)
#define OFF_EB   (OFF_SQP + 256)
#define OFF_P    (OFF_EB + (V_ * D_ / 2))

__device__ __forceinline__ unsigned short f2bf(float x) {
    unsigned u = __float_as_uint(x);
    u += 0x7FFFu + ((u >> 16) & 1u);
    return (unsigned short)(u >> 16);
}
__device__ __forceinline__ float bf2f(unsigned short u) {
    return __uint_as_float(((unsigned)u) << 16);
}

// ---- emb (f32) -> embb (bf16), streaming ----
__global__ __launch_bounds__(256) void prep_kernel(const float* __restrict__ emb,
                                                   unsigned short* __restrict__ embb) {
    const int N4 = V_ * D_ / 4;
    for (int i = blockIdx.x * 256 + threadIdx.x; i < N4; i += gridDim.x * 256) {
        float4 v = ((const float4*)emb)[i];
        ushort4 h;
        h.x = f2bf(v.x); h.y = f2bf(v.y); h.z = f2bf(v.z); h.w = f2bf(v.w);
        ((ushort4*)embb)[i] = h;
    }
}

// ---- Wout (f32 [k][n]) -> Wt (bf16 [n][k]); zero accumulator slots ----
__global__ __launch_bounds__(256) void wt_kernel(const float* __restrict__ Wout,
                                                 unsigned short* __restrict__ Wt,
                                                 float* __restrict__ ws) {
    __shared__ float sT[64][65];
    if (blockIdx.x == 0 && blockIdx.y == 0) {
        int t = threadIdx.x;
        if (t < 16) ((int*)ws)[t] = 0;   // incl. kl_acc at [1]
        ws[OFF_SQP + t] = 0.f;
    }
    const int k0 = blockIdx.x * 64, n0 = blockIdx.y * 64;
    const int c = threadIdx.x & 63, rg = threadIdx.x >> 6;
#pragma unroll
    for (int i = 0; i < 16; ++i) {
        int r = rg * 16 + i;
        sT[c][r] = Wout[(k0 + r) * D_ + n0 + c];
    }
    __syncthreads();
#pragma unroll
    for (int i = 0; i < 16; ++i) {
        int r = rg * 16 + i;
        Wt[(size_t)(n0 + r) * D_ + k0 + c] = f2bf(sT[r][c]);
    }
}

// ---- fused enc + latent (one block per b) ----
__global__ __launch_bounds__(1024) void enclat_kernel(
    const int* __restrict__ vocab, const int* __restrict__ order,
    const int* __restrict__ mask, const float* __restrict__ emb,
    const float* __restrict__ eps,
    const float* __restrict__ Wm, const float* __restrict__ bm,
    const float* __restrict__ Wv, const float* __restrict__ bv,
    const float* __restrict__ Wlin, const float* __restrict__ blin,
    const float* __restrict__ Wout, const float* __restrict__ bout,
    int* __restrict__ lens, float* __restrict__ Q, float* __restrict__ kl_acc) {
    __shared__ int s_id1[S_], s_id2[S_];
    __shared__ float4 s_part[15 * 64];
    __shared__ float s_enc[D_];
    __shared__ float s_mean[L_], s_lv[L_], s_z[L_], s_mem[D_];
    __shared__ float s_red[256];
    __shared__ int s_cnt;
    const int b = blockIdx.x;
    const int tid = threadIdx.x;
    if (tid == 0) s_cnt = 0;
    __syncthreads();
    if (tid < S_) {
        int j = tid;
        int mk = mask[b * S_ + j];
        int id1 = 0, id2 = 0;
        if (mk) {
            id1 = vocab[b * S_ + j];
            if (j == 0) {
                id2 = 1;  // BOS at position 0
            } else {
                int oi = order[(size_t)(b * S_ + j) * 6];
                if (oi == -1) oi = 1;
                id2 = mask[b * S_ + oi] ? vocab[b * S_ + oi] : 0;  // parent from vt
            }
        }
        s_id1[j] = id1;
        s_id2[j] = id2;
        unsigned long long bal = __ballot(mk != 0);
        if ((tid & 63) == 0) atomicAdd(&s_cnt, __popcll(bal));
    }
    __syncthreads();
    const int cnt = s_cnt;  // prefix mask: valid j = [0, cnt)
    if (tid == 0) lens[b] = cnt;
    const int jg = tid >> 6, d4 = tid & 63;
    const float4* emb4 = (const float4*)emb;
    float4 a = {0.f, 0.f, 0.f, 0.f};
#pragma unroll 4
    for (int j = jg; j < cnt; j += 16) {
        float4 x = emb4[(size_t)s_id1[j] * 64 + d4];
        float4 y = emb4[(size_t)s_id2[j] * 64 + d4];
        a.x += x.x + y.x; a.y += x.y + y.y; a.z += x.z + y.z; a.w += x.w + y.w;
    }
    if (jg) s_part[(jg - 1) * 64 + d4] = a;
    __syncthreads();
    if (jg == 0) {
#pragma unroll
        for (int g = 0; g < 15; ++g) {
            float4 p = s_part[g * 64 + d4];
            a.x += p.x; a.y += p.y; a.z += p.z; a.w += p.w;
        }
        float inv = 1.f / fmaxf((float)cnt, 1.f);
        a.x *= inv; a.y *= inv; a.z *= inv; a.w *= inv;
        ((float4*)s_enc)[d4] = a;
    }
    __syncthreads();
    float dot = 0.f;
    if (tid < 256) {
        const int l = tid & (L_ - 1);
        const float* W = (tid < L_) ? Wm : Wv;
        const float* bb = (tid < L_) ? bm : bv;
        dot = bb[l];
        for (int d = 0; d < D_; ++d) dot = fmaf(s_enc[d], W[d * L_ + l], dot);
        if (tid < L_) s_mean[l] = dot; else s_lv[l] = dot;
    }
    __syncthreads();
    float klp = 0.f;
    if (tid < L_) {
        float mn = s_mean[tid], lv = s_lv[tid];
        s_z[tid] = mn + eps[b * L_ + tid] * expf(0.5f * lv);
        klp = 1.f + lv - mn * mn - expf(lv);
    }
    if (tid < 256) s_red[tid] = klp;
    __syncthreads();
    for (int s = 128; s > 0; s >>= 1) {
        if (tid < s) s_red[tid] += s_red[tid + s];
        __syncthreads();
    }
    if (tid == 0) atomicAdd(kl_acc, s_red[0]);
    if (tid < 256) {
        float mem = blin[tid];
        for (int l2 = 0; l2 < L_; ++l2) mem = fmaf(s_z[l2], Wlin[l2 * D_ + tid], mem);
        s_mem[tid] = mem;
    }
    __syncthreads();
    if (tid < 256) {
        float qv = bout[tid];
        for (int k = 0; k < D_; ++k) qv = fmaf(s_mem[k], Wout[k * D_ + tid], qv);
        Q[b * D_ + tid] = qv;
    }
}

// ---- P = embb @ Wout: B-in-registers persistent GEMM ----
// wave wv owns cols [wv*64,+64); B frags (4nt x 8kk) loaded ONCE; stream
// 16-row chunks of embb with A double-buffer. 50000 = 16*3125 exactly.
__global__ __launch_bounds__(256, 2) void pgemm_kernel(
    const unsigned short* __restrict__ embb, const unsigned short* __restrict__ Wt,
    unsigned short* __restrict__ P) {
    const int tid = threadIdx.x;
    const int wv = tid >> 6, lane = tid & 63;
    const int lo = lane & 15, hi = lane >> 4;
    const int NCH = V_ / 16;  // 3125

    short8 bfr[4][8];
    const unsigned short* wbase = Wt + (size_t)(wv * 64 + lo) * D_ + hi * 8;
#pragma unroll
    for (int nt = 0; nt < 4; ++nt)
#pragma unroll
        for (int kk = 0; kk < 8; ++kk)
            bfr[nt][kk] = *(const short8*)(wbase + nt * 16 * D_ + kk * 32);

    int ch = blockIdx.x;
    const unsigned short* abase = embb + (size_t)(ch * 16 + lo) * D_ + hi * 8;
    short8 acur[8];
#pragma unroll
    for (int kk = 0; kk < 8; ++kk) acur[kk] = *(const short8*)(abase + kk * 32);

    for (; ch < NCH; ch += PGRID) {
        // prefetch next chunk's A frags
        const int chn = (ch + PGRID < NCH) ? (ch + PGRID) : ch;
        const unsigned short* anext = embb + (size_t)(chn * 16 + lo) * D_ + hi * 8;
        short8 anxt[8];
#pragma unroll
        for (int kk = 0; kk < 8; ++kk) anxt[kk] = *(const short8*)(anext + kk * 32);

        floatx4 acc[4];
#pragma unroll
        for (int nt = 0; nt < 4; ++nt) acc[nt] = (floatx4){0.f, 0.f, 0.f, 0.f};
#pragma unroll
        for (int kk = 0; kk < 8; ++kk)
#pragma unroll
            for (int nt = 0; nt < 4; ++nt)
                acc[nt] = __builtin_amdgcn_mfma_f32_16x16x32_bf16(
                    acur[kk], bfr[nt][kk], acc[nt], 0, 0, 0);

        // store: row = ch*16 + hi*4 + r, col = wv*64 + nt*16 + lo
#pragma unroll
        for (int r = 0; r < 4; ++r) {
            unsigned short* prow = P + (size_t)(ch * 16 + hi * 4 + r) * D_ + wv * 64 + lo;
#pragma unroll
            for (int nt = 0; nt < 4; ++nt) prow[nt * 16] = f2bf(acc[nt][r]);
        }
#pragma unroll
        for (int kk = 0; kk < 8; ++kk) acur[kk] = anxt[kk];
    }
}

// ---- scan: per position d = P[inp] + Q_b - embb[tgt]; sum d^2 ----
// grid (33 chunks, 256 b); 4 positions per wave, lane covers 4 cols
__global__ __launch_bounds__(256) void scan_kernel(
    const int* __restrict__ vocab, const unsigned short* __restrict__ embb,
    const unsigned short* __restrict__ P, const float* __restrict__ Q,
    const int* __restrict__ lens, float* __restrict__ sqp) {
    const int tid = threadIdx.x;
    const int wv = tid >> 6, lane = tid & 63;
    const int b = blockIdx.y, chunk = blockIdx.x;
    const int len = lens[b];
    const int j0 = chunk * 16 + wv * 4;
    if (j0 > len) return;  // wave-uniform

    const int c = lane * 4;
    const float4 q4 = *(const float4*)(Q + (size_t)b * D_ + c);
    float acc = 0.f;
#pragma unroll
    for (int jj = 0; jj < 4; ++jj) {
        const int j = j0 + jj;
        if (j > len) break;  // wave-uniform
        const int inp = (j == 0) ? 1 : vocab[b * S_ + j - 1];
        const int tgt = (j < len) ? vocab[b * S_ + j] : ((len < S_) ? 2 : 1);
        const ushort4 pv = *(const ushort4*)(P + (size_t)inp * D_ + c);
        const ushort4 tv = *(const ushort4*)(embb + (size_t)tgt * D_ + c);
        float d0 = bf2f(pv.x) + q4.x - bf2f(tv.x);
        float d1 = bf2f(pv.y) + q4.y - bf2f(tv.y);
        float d2 = bf2f(pv.z) + q4.z - bf2f(tv.z);
        float d3 = bf2f(pv.w) + q4.w - bf2f(tv.w);
        acc = fmaf(d0, d0, acc);
        acc = fmaf(d1, d1, acc);
        acc = fmaf(d2, d2, acc);
        acc = fmaf(d3, d3, acc);
    }
#pragma unroll
    for (int off = 32; off; off >>= 1) acc += __shfl_down(acc, off, 64);
    if (lane == 0) atomicAdd(&sqp[(blockIdx.y * 4 + wv + blockIdx.x) & 255], acc);
}

__global__ __launch_bounds__(256) void finalize_kernel(const float* __restrict__ ws,
                                                       float* __restrict__ out) {
    __shared__ float s_sq[256];
    __shared__ int s_vc[256];
    const int tid = threadIdx.x;
    s_sq[tid] = ws[OFF_SQP + tid];
    s_vc[tid] = ((const int*)ws)[OFF_LENS + tid] + 1;  // valid = len + 1 per b
    __syncthreads();
    for (int s = 128; s > 0; s >>= 1) {
        if (tid < s) {
            s_sq[tid] += s_sq[tid + s];
            s_vc[tid] += s_vc[tid + s];
        }
        __syncthreads();
    }
    if (tid == 0) {
        long long denom = (long long)s_vc[0] * D_;
        if (denom < 1) denom = 1;
        out[0] = s_sq[0] / (float)denom;
        out[1] = -0.5f * ws[1] / (float)B_;
    }
}

extern "C" void kernel_launch(void* const* d_in, const int* in_sizes, int n_in,
                              void* d_out, int out_size, void* d_ws, size_t ws_size,
                              hipStream_t stream) {
    const int* vocab = (const int*)d_in[0];
    const int* order = (const int*)d_in[1];
    const int* mask  = (const int*)d_in[2];
    const float* eps  = (const float*)d_in[3];
    const float* emb  = (const float*)d_in[4];
    const float* Wm   = (const float*)d_in[5];
    const float* bm   = (const float*)d_in[6];
    const float* Wv   = (const float*)d_in[7];
    const float* bv   = (const float*)d_in[8];
    const float* Wlin = (const float*)d_in[9];
    const float* blin = (const float*)d_in[10];
    const float* Wout = (const float*)d_in[11];
    const float* bout = (const float*)d_in[12];

    float* ws = (float*)d_ws;
    int* lens = (int*)(ws + OFF_LENS);
    float* Q = ws + OFF_Q;
    unsigned short* Wt = (unsigned short*)(ws + OFF_WT);
    float* sqp = ws + OFF_SQP;
    unsigned short* embb = (unsigned short*)(ws + OFF_EB);
    unsigned short* P = (unsigned short*)(ws + OFF_P);

    wt_kernel<<<dim3(4, 4), 256, 0, stream>>>(Wout, Wt, ws);
    prep_kernel<<<2048, 256, 0, stream>>>(emb, embb);
    enclat_kernel<<<B_, 1024, 0, stream>>>(vocab, order, mask, emb, eps, Wm, bm,
                                           Wv, bv, Wlin, blin, Wout, bout,
                                           lens, Q, ws + 1);
    pgemm_kernel<<<PGRID, 256, 0, stream>>>(embb, Wt, P);
    scan_kernel<<<dim3(33, B_), 256, 0, stream>>>(vocab, embb, P, Q, lens, sqp);
    finalize_kernel<<<1, 256, 0, stream>>>(ws, (float*)d_out);
}

// Round 8
// 181.602 us; speedup vs baseline: 1.4964x; 1.1106x over previous
//
#include <hip/hip_runtime.h>

#define B_ 256
#define S_ 512
#define V_ 50000
#define D_ 256
#define L_ 128
#define PGRID 512

typedef __attribute__((ext_vector_type(8))) short short8;
typedef __attribute__((ext_vector_type(4))) float floatx4;

// ws layout (float units):
// [0] unused, [1] kl_acc (f32), [2..16) unused
// [16 .. +256)        lens (i32)
// [272 .. +65536)     Q (256x256 f32)
// [65808 .. +32768)   Wt (256x256 bf16 = Wout^T)
// [98576 .. +256)     sq partial slots (f32)
// [98832 .. +6400000) embb (50000x256 bf16)
// [6498832 .. +6400000) P (50000x256 bf16 = emb @ Wout)
#define OFF_LENS 16
#define OFF_Q    (OFF_LENS + B_)
#define OFF_WT   (OFF_Q + B_ * D_)
#define OFF_SQP  (OFF_WT + 32768)
#define OFF_EB   (OFF_SQP + 256)
#define OFF_P    (OFF_EB + (V_ * D_ / 2))

__device__ __forceinline__ unsigned short f2bf(float x) {
    unsigned u = __float_as_uint(x);
    u += 0x7FFFu + ((u >> 16) & 1u);
    return (unsigned short)(u >> 16);
}
__device__ __forceinline__ float bf2f(unsigned short u) {
    return __uint_as_float(((unsigned)u) << 16);
}

// ---- fused prep: embb=bf16(emb), Wt=bf16(Wout^T), zero accumulators ----
__global__ __launch_bounds__(256) void prep_kernel(const float* __restrict__ emb,
                                                   const float* __restrict__ Wout,
                                                   unsigned short* __restrict__ embb,
                                                   unsigned short* __restrict__ Wt,
                                                   float* __restrict__ ws) {
    __shared__ float sT[64][65];
    const int tid = threadIdx.x;
    if (blockIdx.x == 0) {
        if (tid < 16) ((int*)ws)[tid] = 0;   // incl. kl_acc at [1]
        ws[OFF_SQP + tid] = 0.f;
    }
    if (blockIdx.x < 16) {  // Wout transpose tile (64x64)
        const int bx = blockIdx.x;
        const int k0 = (bx & 3) * 64, n0 = (bx >> 2) * 64;
        const int c = tid & 63, rg = tid >> 6;
#pragma unroll
        for (int i = 0; i < 16; ++i) {
            int r = rg * 16 + i;
            sT[c][r] = Wout[(k0 + r) * D_ + n0 + c];
        }
        __syncthreads();
#pragma unroll
        for (int i = 0; i < 16; ++i) {
            int r = rg * 16 + i;
            Wt[(size_t)(n0 + r) * D_ + k0 + c] = f2bf(sT[r][c]);
        }
    }
    const int N4 = V_ * D_ / 4;
    for (int i = blockIdx.x * 256 + tid; i < N4; i += gridDim.x * 256) {
        float4 v = ((const float4*)emb)[i];
        ushort4 h;
        h.x = f2bf(v.x); h.y = f2bf(v.y); h.z = f2bf(v.z); h.w = f2bf(v.w);
        ((ushort4*)embb)[i] = h;
    }
}

// ---- fused enc + latent (one block per b); gathers from bf16 embb ----
__global__ __launch_bounds__(1024) void enclat_kernel(
    const int* __restrict__ vocab, const int* __restrict__ order,
    const int* __restrict__ mask, const unsigned short* __restrict__ embb,
    const float* __restrict__ eps,
    const float* __restrict__ Wm, const float* __restrict__ bm,
    const float* __restrict__ Wv, const float* __restrict__ bv,
    const float* __restrict__ Wlin, const float* __restrict__ blin,
    const float* __restrict__ Wout, const float* __restrict__ bout,
    int* __restrict__ lens, float* __restrict__ Q, float* __restrict__ kl_acc) {
    __shared__ int s_id1[S_], s_id2[S_];
    __shared__ float4 s_part[15 * 64];
    __shared__ float s_enc[D_];
    __shared__ float s_mean[L_], s_lv[L_], s_z[L_], s_mem[D_];
    __shared__ float s_red[256];
    __shared__ int s_cnt;
    const int b = blockIdx.x;
    const int tid = threadIdx.x;
    if (tid == 0) s_cnt = 0;
    __syncthreads();
    if (tid < S_) {
        int j = tid;
        int mk = mask[b * S_ + j];
        int id1 = 0, id2 = 0;
        if (mk) {
            id1 = vocab[b * S_ + j];
            if (j == 0) {
                id2 = 1;  // BOS at position 0
            } else {
                int oi = order[(size_t)(b * S_ + j) * 6];
                if (oi == -1) oi = 1;
                id2 = mask[b * S_ + oi] ? vocab[b * S_ + oi] : 0;  // parent from vt
            }
        }
        s_id1[j] = id1;
        s_id2[j] = id2;
        unsigned long long bal = __ballot(mk != 0);
        if ((tid & 63) == 0) atomicAdd(&s_cnt, __popcll(bal));
    }
    __syncthreads();
    const int cnt = s_cnt;  // prefix mask: valid j = [0, cnt)
    if (tid == 0) lens[b] = cnt;
    const int jg = tid >> 6, d4 = tid & 63;
    const ushort4* eb4 = (const ushort4*)embb;
    float4 a = {0.f, 0.f, 0.f, 0.f};
#pragma unroll 4
    for (int j = jg; j < cnt; j += 16) {
        ushort4 x = eb4[(size_t)s_id1[j] * 64 + d4];
        ushort4 y = eb4[(size_t)s_id2[j] * 64 + d4];
        a.x += bf2f(x.x) + bf2f(y.x);
        a.y += bf2f(x.y) + bf2f(y.y);
        a.z += bf2f(x.z) + bf2f(y.z);
        a.w += bf2f(x.w) + bf2f(y.w);
    }
    if (jg) s_part[(jg - 1) * 64 + d4] = a;
    __syncthreads();
    if (jg == 0) {
#pragma unroll
        for (int g = 0; g < 15; ++g) {
            float4 p = s_part[g * 64 + d4];
            a.x += p.x; a.y += p.y; a.z += p.z; a.w += p.w;
        }
        float inv = 1.f / fmaxf((float)cnt, 1.f);
        a.x *= inv; a.y *= inv; a.z *= inv; a.w *= inv;
        ((float4*)s_enc)[d4] = a;
    }
    __syncthreads();
    float dot = 0.f;
    if (tid < 256) {
        const int l = tid & (L_ - 1);
        const float* W = (tid < L_) ? Wm : Wv;
        const float* bb = (tid < L_) ? bm : bv;
        dot = bb[l];
        for (int d = 0; d < D_; ++d) dot = fmaf(s_enc[d], W[d * L_ + l], dot);
        if (tid < L_) s_mean[l] = dot; else s_lv[l] = dot;
    }
    __syncthreads();
    float klp = 0.f;
    if (tid < L_) {
        float mn = s_mean[tid], lv = s_lv[tid];
        s_z[tid] = mn + eps[b * L_ + tid] * expf(0.5f * lv);
        klp = 1.f + lv - mn * mn - expf(lv);
    }
    if (tid < 256) s_red[tid] = klp;
    __syncthreads();
    for (int s = 128; s > 0; s >>= 1) {
        if (tid < s) s_red[tid] += s_red[tid + s];
        __syncthreads();
    }
    if (tid == 0) atomicAdd(kl_acc, s_red[0]);
    if (tid < 256) {
        float mem = blin[tid];
        for (int l2 = 0; l2 < L_; ++l2) mem = fmaf(s_z[l2], Wlin[l2 * D_ + tid], mem);
        s_mem[tid] = mem;
    }
    __syncthreads();
    if (tid < 256) {
        float qv = bout[tid];
        for (int k = 0; k < D_; ++k) qv = fmaf(s_mem[k], Wout[k * D_ + tid], qv);
        Q[b * D_ + tid] = qv;
    }
}

// ---- P = embb @ Wout: B-in-registers persistent GEMM ----
__global__ __launch_bounds__(256, 2) void pgemm_kernel(
    const unsigned short* __restrict__ embb, const unsigned short* __restrict__ Wt,
    unsigned short* __restrict__ P) {
    const int tid = threadIdx.x;
    const int wv = tid >> 6, lane = tid & 63;
    const int lo = lane & 15, hi = lane >> 4;
    const int NCH = V_ / 16;  // 3125

    short8 bfr[4][8];
    const unsigned short* wbase = Wt + (size_t)(wv * 64 + lo) * D_ + hi * 8;
#pragma unroll
    for (int nt = 0; nt < 4; ++nt)
#pragma unroll
        for (int kk = 0; kk < 8; ++kk)
            bfr[nt][kk] = *(const short8*)(wbase + nt * 16 * D_ + kk * 32);

    int ch = blockIdx.x;
    const unsigned short* abase = embb + (size_t)(ch * 16 + lo) * D_ + hi * 8;
    short8 acur[8];
#pragma unroll
    for (int kk = 0; kk < 8; ++kk) acur[kk] = *(const short8*)(abase + kk * 32);

    for (; ch < NCH; ch += PGRID) {
        const int chn = (ch + PGRID < NCH) ? (ch + PGRID) : ch;
        const unsigned short* anext = embb + (size_t)(chn * 16 + lo) * D_ + hi * 8;
        short8 anxt[8];
#pragma unroll
        for (int kk = 0; kk < 8; ++kk) anxt[kk] = *(const short8*)(anext + kk * 32);

        floatx4 acc[4];
#pragma unroll
        for (int nt = 0; nt < 4; ++nt) acc[nt] = (floatx4){0.f, 0.f, 0.f, 0.f};
#pragma unroll
        for (int kk = 0; kk < 8; ++kk)
#pragma unroll
            for (int nt = 0; nt < 4; ++nt)
                acc[nt] = __builtin_amdgcn_mfma_f32_16x16x32_bf16(
                    acur[kk], bfr[nt][kk], acc[nt], 0, 0, 0);

#pragma unroll
        for (int r = 0; r < 4; ++r) {
            unsigned short* prow = P + (size_t)(ch * 16 + hi * 4 + r) * D_ + wv * 64 + lo;
#pragma unroll
            for (int nt = 0; nt < 4; ++nt) prow[nt * 16] = f2bf(acc[nt][r]);
        }
#pragma unroll
        for (int kk = 0; kk < 8; ++kk) acur[kk] = anxt[kk];
    }
}

// ---- scan v2: 8 positions/wave, phase-split loads, predicated accumulate ----
__global__ __launch_bounds__(256) void scan_kernel(
    const int* __restrict__ vocab, const unsigned short* __restrict__ embb,
    const unsigned short* __restrict__ P, const float* __restrict__ Q,
    const int* __restrict__ lens, float* __restrict__ sqp) {
    const int tid = threadIdx.x;
    const int wv = tid >> 6, lane = tid & 63;
    const int b = blockIdx.y, chunk = blockIdx.x;
    const int len = lens[b];
    const int j0 = chunk * 32 + wv * 8;
    if (j0 > len) return;  // wave-uniform

    const int c = lane * 4;
    const float4 q4 = *(const float4*)(Q + (size_t)b * D_ + c);

    int inp[8], tgt[8];
    float wgt[8];
#pragma unroll
    for (int jj = 0; jj < 8; ++jj) {
        const int j = j0 + jj;
        const bool v = (j <= len);
        const int jc = v ? j : 0;
        inp[jj] = (jc == 0) ? 1 : vocab[b * S_ + jc - 1];
        tgt[jj] = v ? ((j < len) ? vocab[b * S_ + j] : ((len < S_) ? 2 : 1)) : 1;
        wgt[jj] = v ? 1.f : 0.f;
    }
    ushort4 pv[8], tv[8];
#pragma unroll
    for (int jj = 0; jj < 8; ++jj) {
        pv[jj] = *(const ushort4*)(P + (size_t)inp[jj] * D_ + c);
        tv[jj] = *(const ushort4*)(embb + (size_t)tgt[jj] * D_ + c);
    }
    float acc = 0.f;
#pragma unroll
    for (int jj = 0; jj < 8; ++jj) {
        float d0 = bf2f(pv[jj].x) + q4.x - bf2f(tv[jj].x);
        float d1 = bf2f(pv[jj].y) + q4.y - bf2f(tv[jj].y);
        float d2 = bf2f(pv[jj].z) + q4.z - bf2f(tv[jj].z);
        float d3 = bf2f(pv[jj].w) + q4.w - bf2f(tv[jj].w);
        float s = fmaf(d0, d0, fmaf(d1, d1, fmaf(d2, d2, d3 * d3)));
        acc = fmaf(wgt[jj], s, acc);
    }
#pragma unroll
    for (int off = 32; off; off >>= 1) acc += __shfl_down(acc, off, 64);
    if (lane == 0) atomicAdd(&sqp[(b * 4 + wv + chunk) & 255], acc);
}

__global__ __launch_bounds__(256) void finalize_kernel(const float* __restrict__ ws,
                                                       float* __restrict__ out) {
    __shared__ float s_sq[256];
    __shared__ int s_vc[256];
    const int tid = threadIdx.x;
    s_sq[tid] = ws[OFF_SQP + tid];
    s_vc[tid] = ((const int*)ws)[OFF_LENS + tid] + 1;  // valid = len + 1 per b
    __syncthreads();
    for (int s = 128; s > 0; s >>= 1) {
        if (tid < s) {
            s_sq[tid] += s_sq[tid + s];
            s_vc[tid] += s_vc[tid + s];
        }
        __syncthreads();
    }
    if (tid == 0) {
        long long denom = (long long)s_vc[0] * D_;
        if (denom < 1) denom = 1;
        out[0] = s_sq[0] / (float)denom;
        out[1] = -0.5f * ws[1] / (float)B_;
    }
}

extern "C" void kernel_launch(void* const* d_in, const int* in_sizes, int n_in,
                              void* d_out, int out_size, void* d_ws, size_t ws_size,
                              hipStream_t stream) {
    const int* vocab = (const int*)d_in[0];
    const int* order = (const int*)d_in[1];
    const int* mask  = (const int*)d_in[2];
    const float* eps  = (const float*)d_in[3];
    const float* emb  = (const float*)d_in[4];
    const float* Wm   = (const float*)d_in[5];
    const float* bm   = (const float*)d_in[6];
    const float* Wv   = (const float*)d_in[7];
    const float* bv   = (const float*)d_in[8];
    const float* Wlin = (const float*)d_in[9];
    const float* blin = (const float*)d_in[10];
    const float* Wout = (const float*)d_in[11];
    const float* bout = (const float*)d_in[12];

    float* ws = (float*)d_ws;
    int* lens = (int*)(ws + OFF_LENS);
    float* Q = ws + OFF_Q;
    unsigned short* Wt = (unsigned short*)(ws + OFF_WT);
    float* sqp = ws + OFF_SQP;
    unsigned short* embb = (unsigned short*)(ws + OFF_EB);
    unsigned short* P = (unsigned short*)(ws + OFF_P);

    prep_kernel<<<2048, 256, 0, stream>>>(emb, Wout, embb, Wt, ws);
    enclat_kernel<<<B_, 1024, 0, stream>>>(vocab, order, mask, embb, eps, Wm, bm,
                                           Wv, bv, Wlin, blin, Wout, bout,
                                           lens, Q, ws + 1);
    pgemm_kernel<<<PGRID, 256, 0, stream>>>(embb, Wt, P);
    scan_kernel<<<dim3(17, B_), 256, 0, stream>>>(vocab, embb, P, Q, lens, sqp);
    finalize_kernel<<<1, 256, 0, stream>>>(ws, (float*)d_out);
}